// Round 1
// baseline (621.271 us; speedup 1.0000x reference)
//
#include <hip/hip_runtime.h>
#include <hip/hip_bf16.h>

#define NN 8192
#define CH 256

typedef float f32x4 __attribute__((ext_vector_type(4)));
typedef __bf16 bf16x8 __attribute__((ext_vector_type(8)));

union FragU { uint4 u; bf16x8 h; };

static __device__ __forceinline__ unsigned short f2bf(float f) {
  union { float f; unsigned int u; } v; v.f = f;
  unsigned int x = v.u;
  return (unsigned short)((x + 0x7fffu + ((x >> 16) & 1u)) >> 16);  // RNE
}

// ---------------- kernel 1: build HT[j][k] = bf16(d[k]*H[k][j]), WT[j][c] = bf16(W[c][j])
__global__ __launch_bounds__(256) void k_prep(const float* __restrict__ Hm,
                                              const float* __restrict__ Dm,
                                              const float* __restrict__ Wm,
                                              unsigned short* __restrict__ HT,
                                              unsigned short* __restrict__ WT) {
  __shared__ float tile[64][65];
  int bx = blockIdx.x, t = threadIdx.x;
  bool isH = bx < 512;
  int b = isH ? bx : bx - 512;
  int r0 = (b >> 2) * 64;          // source row base (k for H, c for W)
  int j0 = (b & 3) * 64;           // source col base
  const float* src = isH ? Hm : Wm;

  int r = t >> 2;
  int cq = (t & 3) * 16;
  float dval = isH ? rsqrtf(Dm[(size_t)(r0 + r) * (NN + 1)]) : 1.0f;
  const float* p = src + (size_t)(r0 + r) * CH + j0 + cq;
#pragma unroll
  for (int u = 0; u < 4; ++u) {
    float4 v = *(const float4*)(p + u * 4);
    tile[r][cq + u * 4 + 0] = v.x * dval;
    tile[r][cq + u * 4 + 1] = v.y * dval;
    tile[r][cq + u * 4 + 2] = v.z * dval;
    tile[r][cq + u * 4 + 3] = v.w * dval;
  }
  __syncthreads();
  int j = t >> 2;
  int kq = (t & 3) * 16;
  __align__(16) unsigned short ov[16];
#pragma unroll
  for (int i = 0; i < 16; ++i) ov[i] = f2bf(tile[kq + i][j]);
  unsigned short* dst = isH ? (HT + (size_t)(j0 + j) * NN + r0 + kq)
                            : (WT + (size_t)(j0 + j) * CH + r0 + kq);
  *(uint4*)dst = *(uint4*)ov;
  *(uint4*)(dst + 8) = *(uint4*)(ov + 8);
}

// ---------------- kernel 2: split-K GEMM  P[s][i][j] = sum_k bf16(A[i,k]) * HT[j,k]
__global__ __launch_bounds__(256) void k_gemm1(const float* __restrict__ A,
                                               const unsigned short* __restrict__ HT,
                                               float* __restrict__ P) {
  __shared__ unsigned short As[64][72];    // stride 72 (36 dwords) -> even bank-group spread
  __shared__ unsigned short Bs[256][72];
  int bx = blockIdx.x;
  int strip = bx >> 1, s = bx & 1;
  int i0 = strip * 64;
  int kbase = s * 4096;
  int t = threadIdx.x, l = t & 63, w = t >> 6;
  int lan = l & 15, quad = l >> 4;

  int ar = t >> 2, aq = (t & 3) * 16;              // A staging: row, 16-float chunk
  const float* Ap = A + (size_t)(i0 + ar) * NN + kbase + aq;
  int bn = t >> 3, bc = (t & 7) * 8;               // B staging: 8 rows/instr, 16B chunks
  const unsigned short* Bp = HT + (size_t)bn * NN + kbase + bc;

  float4 areg[4];
  uint4 breg[8];
  f32x4 acc[4][4];
#pragma unroll
  for (int mt = 0; mt < 4; ++mt)
#pragma unroll
    for (int nt = 0; nt < 4; ++nt)
#pragma unroll
      for (int c = 0; c < 4; ++c) acc[mt][nt][c] = 0.0f;

  // prologue: load tile 0
#pragma unroll
  for (int u = 0; u < 4; ++u) areg[u] = *(const float4*)(Ap + u * 4);
#pragma unroll
  for (int j = 0; j < 8; ++j) breg[j] = *(const uint4*)(Bp + (size_t)j * 32 * NN);

  for (int kt = 0; kt < 64; ++kt) {
    __syncthreads();   // previous compute done reading LDS
    // stage A: fp32 -> bf16
#pragma unroll
    for (int u = 0; u < 4; ++u) {
      float4 v = areg[u];
      union { unsigned short h[4]; uint2 u2; } pk;
      pk.h[0] = f2bf(v.x); pk.h[1] = f2bf(v.y); pk.h[2] = f2bf(v.z); pk.h[3] = f2bf(v.w);
      *(uint2*)&As[ar][aq + u * 4] = pk.u2;
    }
    // stage B
#pragma unroll
    for (int j = 0; j < 8; ++j) *(uint4*)&Bs[j * 32 + bn][bc] = breg[j];
    __syncthreads();
    // prefetch next tile into regs (overlaps with MFMA below)
    if (kt < 63) {
      const float* Ap2 = Ap + (kt + 1) * 64;
#pragma unroll
      for (int u = 0; u < 4; ++u) areg[u] = *(const float4*)(Ap2 + u * 4);
      const unsigned short* Bp2 = Bp + (kt + 1) * 64;
#pragma unroll
      for (int j = 0; j < 8; ++j) breg[j] = *(const uint4*)(Bp2 + (size_t)j * 32 * NN);
    }
    // compute: 2 k-steps of 16x16x32, wave tile 64x64
#pragma unroll
    for (int ss = 0; ss < 2; ++ss) {
      FragU af[4], bfr[4];
#pragma unroll
      for (int mt = 0; mt < 4; ++mt)
        af[mt].u = *(const uint4*)&As[mt * 16 + lan][ss * 32 + quad * 8];
#pragma unroll
      for (int nt = 0; nt < 4; ++nt)
        bfr[nt].u = *(const uint4*)&Bs[w * 64 + nt * 16 + lan][ss * 32 + quad * 8];
#pragma unroll
      for (int mt = 0; mt < 4; ++mt)
#pragma unroll
        for (int nt = 0; nt < 4; ++nt)
          acc[mt][nt] = __builtin_amdgcn_mfma_f32_16x16x32_bf16(af[mt].h, bfr[nt].h, acc[mt][nt], 0, 0, 0);
    }
  }
  // epilogue: write fp32 partial (C/D layout: col=lane&15, row=quad*4+reg)
  float* Pp = P + (size_t)s * NN * CH;
#pragma unroll
  for (int mt = 0; mt < 4; ++mt) {
    int i = i0 + mt * 16 + quad * 4;
#pragma unroll
    for (int nt = 0; nt < 4; ++nt) {
      int jc = w * 64 + nt * 16 + lan;
#pragma unroll
      for (int r = 0; r < 4; ++r)
        Pp[(size_t)(i + r) * CH + jc] = acc[mt][nt][r];
    }
  }
}

// ---------------- kernel 3: out[i][j2] = sum_c ( d[i]*(P0+P1)[i][c] ) * WT[j2][c]
__global__ __launch_bounds__(256) void k_gemm2(const float* __restrict__ P,
                                               const float* __restrict__ Dm,
                                               const unsigned short* __restrict__ WT,
                                               float* __restrict__ out) {
  __shared__ unsigned short Gs[32][264];
  __shared__ unsigned short Ws[64][264];
  int bx = blockIdx.x, t = threadIdx.x, l = t & 63, w = t >> 6;
  int lan = l & 15, quad = l >> 4;
  int i0 = bx * 32;
  // build G = bf16(d[i] * (P0+P1))
  {
    int r = t >> 3, c0 = (t & 7) * 32;
    float dval = rsqrtf(Dm[(size_t)(i0 + r) * (NN + 1)]);
    const float* p0 = P + (size_t)(i0 + r) * CH + c0;
    const float* p1 = p0 + (size_t)NN * CH;
    __align__(16) unsigned short g[32];
#pragma unroll
    for (int u = 0; u < 8; ++u) {
      float4 a = *(const float4*)(p0 + u * 4);
      float4 b = *(const float4*)(p1 + u * 4);
      g[u * 4 + 0] = f2bf((a.x + b.x) * dval);
      g[u * 4 + 1] = f2bf((a.y + b.y) * dval);
      g[u * 4 + 2] = f2bf((a.z + b.z) * dval);
      g[u * 4 + 3] = f2bf((a.w + b.w) * dval);
    }
#pragma unroll
    for (int u = 0; u < 4; ++u) *(uint4*)&Gs[r][c0 + u * 8] = *(uint4*)(g + u * 8);
  }
  // 4 strips of 64 output channels
  for (int jt = 0; jt < 4; ++jt) {
    __syncthreads();   // also covers Gs writes on first iter; Ws reads on later iters
    {
      int nrow = t >> 2, cb = (t & 3) * 64;
      const unsigned short* wp = WT + (size_t)(jt * 64 + nrow) * CH + cb;
#pragma unroll
      for (int u = 0; u < 8; ++u) *(uint4*)&Ws[nrow][cb + u * 8] = *(const uint4*)(wp + u * 8);
    }
    __syncthreads();
    f32x4 acc[2];
#pragma unroll
    for (int mt = 0; mt < 2; ++mt)
#pragma unroll
      for (int c = 0; c < 4; ++c) acc[mt][c] = 0.0f;
#pragma unroll
    for (int ks = 0; ks < 8; ++ks) {
      FragU af0, af1, bfr;
      af0.u = *(const uint4*)&Gs[lan][ks * 32 + quad * 8];
      af1.u = *(const uint4*)&Gs[16 + lan][ks * 32 + quad * 8];
      bfr.u = *(const uint4*)&Ws[w * 16 + lan][ks * 32 + quad * 8];
      acc[0] = __builtin_amdgcn_mfma_f32_16x16x32_bf16(af0.h, bfr.h, acc[0], 0, 0, 0);
      acc[1] = __builtin_amdgcn_mfma_f32_16x16x32_bf16(af1.h, bfr.h, acc[1], 0, 0, 0);
    }
#pragma unroll
    for (int mt = 0; mt < 2; ++mt) {
      int i = i0 + mt * 16 + quad * 4;
      int jc = jt * 64 + w * 16 + lan;
#pragma unroll
      for (int r = 0; r < 4; ++r)
        out[(size_t)(i + r) * CH + jc] = acc[mt][r];
    }
  }
}

extern "C" void kernel_launch(void* const* d_in, const int* in_sizes, int n_in,
                              void* d_out, int out_size, void* d_ws, size_t ws_size,
                              hipStream_t stream) {
  const float* A  = (const float*)d_in[0];
  const float* Dm = (const float*)d_in[1];
  const float* Hm = (const float*)d_in[2];
  const float* Wm = (const float*)d_in[3];
  float* out = (float*)d_out;
  char* ws = (char*)d_ws;
  unsigned short* HT = (unsigned short*)ws;                               // 256*8192*2  = 4 MiB
  unsigned short* WT = (unsigned short*)(ws + (size_t)4194304);           // 256*256*2   = 128 KiB
  float* P = (float*)(ws + (size_t)4194304 + 131072);                     // 2*8192*256*4 = 16 MiB

  hipLaunchKernelGGL(k_prep,  dim3(528), dim3(256), 0, stream, Hm, Dm, Wm, HT, WT);
  hipLaunchKernelGGL(k_gemm1, dim3(256), dim3(256), 0, stream, A, HT, P);
  hipLaunchKernelGGL(k_gemm2, dim3(256), dim3(256), 0, stream, P, Dm, WT, out);
}

// Round 2
// 507.665 us; speedup vs baseline: 1.2238x; 1.2238x over previous
//
#include <hip/hip_runtime.h>
#include <hip/hip_bf16.h>

#define NN 8192
#define CH 256

typedef float f32x4 __attribute__((ext_vector_type(4)));
typedef __bf16 bf16x8 __attribute__((ext_vector_type(8)));

union FragU { uint4 u; bf16x8 h; };

static __device__ __forceinline__ unsigned short f2bf(float f) {
  union { float f; unsigned int u; } v; v.f = f;
  unsigned int x = v.u;
  return (unsigned short)((x + 0x7fffu + ((x >> 16) & 1u)) >> 16);  // RNE
}

// ---------------- kernel 1: HT[j][k] = bf16(d[k]*H[k][j]), WT[j][c] = bf16(W[c][j])
__global__ __launch_bounds__(256) void k_prep(const float* __restrict__ Hm,
                                              const float* __restrict__ Dm,
                                              const float* __restrict__ Wm,
                                              unsigned short* __restrict__ HT,
                                              unsigned short* __restrict__ WT) {
  __shared__ float tile[64][65];
  int bx = blockIdx.x, t = threadIdx.x;
  bool isH = bx < 512;
  int b = isH ? bx : bx - 512;
  int r0 = (b >> 2) * 64;
  int j0 = (b & 3) * 64;
  const float* src = isH ? Hm : Wm;

  int r = t >> 2;
  int cq = (t & 3) * 16;
  float dval = isH ? rsqrtf(Dm[(size_t)(r0 + r) * (NN + 1)]) : 1.0f;
  const float* p = src + (size_t)(r0 + r) * CH + j0 + cq;
#pragma unroll
  for (int u = 0; u < 4; ++u) {
    float4 v = *(const float4*)(p + u * 4);
    tile[r][cq + u * 4 + 0] = v.x * dval;
    tile[r][cq + u * 4 + 1] = v.y * dval;
    tile[r][cq + u * 4 + 2] = v.z * dval;
    tile[r][cq + u * 4 + 3] = v.w * dval;
  }
  __syncthreads();
  int j = t >> 2;
  int kq = (t & 3) * 16;
  __align__(16) unsigned short ov[16];
#pragma unroll
  for (int i = 0; i < 16; ++i) ov[i] = f2bf(tile[kq + i][j]);
  unsigned short* dst = isH ? (HT + (size_t)(j0 + j) * NN + r0 + kq)
                            : (WT + (size_t)(j0 + j) * CH + r0 + kq);
  *(uint4*)dst = *(uint4*)ov;
  *(uint4*)(dst + 8) = *(uint4*)(ov + 8);
}

// ---------------- kernel 2: split-K GEMM  P[s][i][j] = sum_k bf16(A[i,k]) * HT[j,k]
// A via LDS (shared across 4 waves, depth-2 reg prefetch); B frags straight from
// L2-resident HT into registers (depth-1 prefetch). LDS = 9.2 KB only.
template <int SK>
__global__ __launch_bounds__(256, 2) void k_gemm1(const float* __restrict__ A,
                                                  const unsigned short* __restrict__ HT,
                                                  float* __restrict__ P) {
  constexpr int KC = NN / SK;   // K-chunk per block
  constexpr int NIT = KC / 64;  // BK=64 iterations (even)
  __shared__ unsigned short As[64][72];  // stride 72 halfs = 36 dwords: 2-way (free) frag reads
  const int bx = blockIdx.x;
  const int strip = bx / SK, s = bx % SK;
  const int i0 = strip * 64, kbase = s * KC;
  const int t = threadIdx.x, l = t & 63, w = t >> 6;
  const int lan = l & 15, quad = l >> 4;

  const int ar = t >> 2, aq = (t & 3) * 16;  // A staging: 16 rows x 64B lines per instr
  const float* Ap = A + (size_t)(i0 + ar) * NN + kbase + aq;
  // B frag base: row (w*64 + lan [+nt*16]), col kbase + quad*8 [+ss*32 + kt*64]
  const unsigned short* Bb = HT + (size_t)(w * 64 + lan) * NN + kbase + quad * 8;

  float4 a0[4], a1[4];
  FragU bc[8], bn[8];
  f32x4 acc[4][4];
#pragma unroll
  for (int mt = 0; mt < 4; ++mt)
#pragma unroll
    for (int nt = 0; nt < 4; ++nt)
#pragma unroll
      for (int c = 0; c < 4; ++c) acc[mt][nt][c] = 0.0f;

  auto loadA = [&](float4 (&dst)[4], int kt) {
    const float* p = Ap + kt * 64;
#pragma unroll
    for (int u = 0; u < 4; ++u) dst[u] = *(const float4*)(p + u * 4);
  };
  auto loadB = [&](FragU (&dst)[8], int kt) {
    const unsigned short* p = Bb + kt * 64;
#pragma unroll
    for (int ss = 0; ss < 2; ++ss)
#pragma unroll
      for (int nt = 0; nt < 4; ++nt)
        dst[ss * 4 + nt].u = *(const uint4*)(p + (size_t)nt * 16 * NN + ss * 32);
  };
  auto storeA = [&](float4 (&src)[4]) {
#pragma unroll
    for (int u = 0; u < 4; ++u) {
      float4 v = src[u];
      union { unsigned short h[4]; uint2 u2; } pk;
      pk.h[0] = f2bf(v.x); pk.h[1] = f2bf(v.y); pk.h[2] = f2bf(v.z); pk.h[3] = f2bf(v.w);
      *(uint2*)&As[ar][aq + u * 4] = pk.u2;
    }
  };
  auto compute = [&](FragU (&b)[8]) {
#pragma unroll
    for (int ss = 0; ss < 2; ++ss) {
      FragU af[4];
#pragma unroll
      for (int mt = 0; mt < 4; ++mt)
        af[mt].u = *(const uint4*)&As[mt * 16 + lan][ss * 32 + quad * 8];
#pragma unroll
      for (int mt = 0; mt < 4; ++mt)
#pragma unroll
        for (int nt = 0; nt < 4; ++nt)
          acc[mt][nt] = __builtin_amdgcn_mfma_f32_16x16x32_bf16(af[mt].h, b[ss * 4 + nt].h,
                                                                acc[mt][nt], 0, 0, 0);
    }
  };

  loadA(a0, 0);
  loadA(a1, 1);
  loadB(bc, 0);

  for (int kt = 0; kt < NIT; kt += 2) {
    // even iteration: tile kt
    __syncthreads();
    storeA(a0);           // waits only on a0's loads (issued 2 iters ago)
    __syncthreads();
    if (kt + 2 < NIT) loadA(a0, kt + 2);
    loadB(bn, kt + 1);    // kt+1 <= NIT-1 always
    compute(bc);
    // odd iteration: tile kt+1
    __syncthreads();
    storeA(a1);
    __syncthreads();
    if (kt + 3 < NIT) loadA(a1, kt + 3);
    if (kt + 2 < NIT) loadB(bc, kt + 2);
    compute(bn);
  }

  float* Pp = P + ((size_t)s * NN + i0) * CH;
#pragma unroll
  for (int mt = 0; mt < 4; ++mt)
#pragma unroll
    for (int nt = 0; nt < 4; ++nt)
#pragma unroll
      for (int r = 0; r < 4; ++r)
        Pp[(size_t)(mt * 16 + quad * 4 + r) * CH + w * 64 + nt * 16 + lan] = acc[mt][nt][r];
}

// ---------------- kernel 3: out[i][j] = sum_c ( d[i]*sum_s P[s][i][c] ) * WT[j][c]
// 512 blocks x 16 rows; G in LDS; W frags straight from L2-hot WT.
template <int SK>
__global__ __launch_bounds__(256) void k_gemm2(const float* __restrict__ P,
                                               const float* __restrict__ Dm,
                                               const unsigned short* __restrict__ WT,
                                               float* __restrict__ out) {
  __shared__ unsigned short Gs[16][264];
  const int bx = blockIdx.x, t = threadIdx.x, l = t & 63, w = t >> 6;
  const int lan = l & 15, quad = l >> 4;
  const int i0 = bx * 16;
  {
    const int r = t >> 4, c0 = (t & 15) * 16;
    float dval = rsqrtf(Dm[(size_t)(i0 + r) * (NN + 1)]);
    const float* pp = P + (size_t)(i0 + r) * CH + c0;
    __align__(16) unsigned short g[16];
#pragma unroll
    for (int u = 0; u < 4; ++u) {
      float sx = 0.f, sy = 0.f, sz = 0.f, sw = 0.f;
#pragma unroll
      for (int s = 0; s < SK; ++s) {
        float4 v = *(const float4*)(pp + (size_t)s * NN * CH + u * 4);
        sx += v.x; sy += v.y; sz += v.z; sw += v.w;
      }
      g[u * 4 + 0] = f2bf(sx * dval);
      g[u * 4 + 1] = f2bf(sy * dval);
      g[u * 4 + 2] = f2bf(sz * dval);
      g[u * 4 + 3] = f2bf(sw * dval);
    }
    *(uint4*)&Gs[r][c0] = *(uint4*)g;
    *(uint4*)&Gs[r][c0 + 8] = *(uint4*)(g + 8);
  }
  __syncthreads();
  const int j0 = w * 64;
  f32x4 acc[4];
#pragma unroll
  for (int nt = 0; nt < 4; ++nt)
#pragma unroll
    for (int c = 0; c < 4; ++c) acc[nt][c] = 0.0f;
#pragma unroll
  for (int ks = 0; ks < 8; ++ks) {
    FragU af;
    af.u = *(const uint4*)&Gs[lan][ks * 32 + quad * 8];
#pragma unroll
    for (int nt = 0; nt < 4; ++nt) {
      FragU bw;
      bw.u = *(const uint4*)&WT[(size_t)(j0 + nt * 16 + lan) * CH + ks * 32 + quad * 8];
      acc[nt] = __builtin_amdgcn_mfma_f32_16x16x32_bf16(af.h, bw.h, acc[nt], 0, 0, 0);
    }
  }
#pragma unroll
  for (int nt = 0; nt < 4; ++nt)
#pragma unroll
    for (int r = 0; r < 4; ++r)
      out[(size_t)(i0 + quad * 4 + r) * CH + j0 + nt * 16 + lan] = acc[nt][r];
}

extern "C" void kernel_launch(void* const* d_in, const int* in_sizes, int n_in,
                              void* d_out, int out_size, void* d_ws, size_t ws_size,
                              hipStream_t stream) {
  const float* A  = (const float*)d_in[0];
  const float* Dm = (const float*)d_in[1];
  const float* Hm = (const float*)d_in[2];
  const float* Wm = (const float*)d_in[3];
  float* out = (float*)d_out;
  char* ws = (char*)d_ws;
  unsigned short* HT = (unsigned short*)ws;                       // 4 MiB
  unsigned short* WT = (unsigned short*)(ws + (size_t)4194304);   // 128 KiB
  float* P = (float*)(ws + (size_t)4194304 + 131072);             // SK * 8 MiB

  const size_t base = 4194304 + 131072;
  const size_t needS4 = base + (size_t)4 * NN * CH * 4;           // ~36.2 MiB

  hipLaunchKernelGGL(k_prep, dim3(528), dim3(256), 0, stream, Hm, Dm, Wm, HT, WT);
  if (ws_size >= needS4) {
    hipLaunchKernelGGL((k_gemm1<4>), dim3(512), dim3(256), 0, stream, A, HT, P);
    hipLaunchKernelGGL((k_gemm2<4>), dim3(512), dim3(256), 0, stream, P, Dm, WT, out);
  } else {
    hipLaunchKernelGGL((k_gemm1<2>), dim3(256), dim3(256), 0, stream, A, HT, P);
    hipLaunchKernelGGL((k_gemm2<2>), dim3(512), dim3(256), 0, stream, P, Dm, WT, out);
  }
}